// Round 1
// 1691.771 us; speedup vs baseline: 1.0681x; 1.0681x over previous
//
#include <hip/hip_runtime.h>

#define LTOT 21952      // 28^3
#define NTOK 343        // 7^3

typedef unsigned short u16;
typedef unsigned int   u32;
typedef __attribute__((ext_vector_type(8))) short short8;
typedef __attribute__((ext_vector_type(4))) float float4v;

__device__ __forceinline__ u16 f2b(float f){
  u32 x = __float_as_uint(f);
  u32 r = (x + 0x7fffu + ((x>>16)&1u)) >> 16;
  return (u16)r;
}

// ---------------- LayerNorm (norm1) : f32 in -> f32 out --------------------
__global__ __launch_bounds__(64) void k_ln(const float* __restrict__ mov, const float* __restrict__ fix,
                                           const float* __restrict__ g, const float* __restrict__ b,
                                           float* __restrict__ om, float* __restrict__ of){
  int row = blockIdx.x;
  const float* src; float* dst;
  if (row < LTOT){ src = mov + (size_t)row*192; dst = om + (size_t)row*192; }
  else          { src = fix + (size_t)(row-LTOT)*192; dst = of + (size_t)(row-LTOT)*192; }
  int t = threadIdx.x;
  float x0 = src[t], x1 = src[t+64], x2 = src[t+128];
  float s = x0+x1+x2, s2 = x0*x0 + x1*x1 + x2*x2;
  for (int o=32;o;o>>=1){ s += __shfl_xor(s,o); s2 += __shfl_xor(s2,o); }
  float mu = s*(1.f/192.f);
  float var = s2*(1.f/192.f) - mu*mu;
  float rs = rsqrtf(var + 1e-5f);
  dst[t]     = (x0-mu)*rs*g[t]     + b[t];
  dst[t+64]  = (x1-mu)*rs*g[t+64]  + b[t+64];
  dst[t+128] = (x2-mu)*rs*g[t+128] + b[t+128];
}

// ---------------- LayerNorm (norm2), single buffer -------------------------
__global__ __launch_bounds__(64) void k_ln1(const float* __restrict__ x,
                                            const float* __restrict__ g, const float* __restrict__ b,
                                            float* __restrict__ y){
  int row = blockIdx.x;
  const float* src = x + (size_t)row*192;
  float* dst = y + (size_t)row*192;
  int t = threadIdx.x;
  float x0 = src[t], x1 = src[t+64], x2 = src[t+128];
  float s = x0+x1+x2, s2 = x0*x0 + x1*x1 + x2*x2;
  for (int o=32;o;o>>=1){ s += __shfl_xor(s,o); s2 += __shfl_xor(s2,o); }
  float mu = s*(1.f/192.f);
  float var = s2*(1.f/192.f) - mu*mu;
  float rs = rsqrtf(var + 1e-5f);
  dst[t]     = (x0-mu)*rs*g[t]     + b[t];
  dst[t+64]  = (x1-mu)*rs*g[t+64]  + b[t+64];
  dst[t+128] = (x2-mu)*rs*g[t+128] + b[t+128];
}

// ------ conv1 weight prep: (192,384,27) f32 -> [n][t*384+c] bf16 -----------
__global__ void k_prepw1b(const float* __restrict__ src, u16* __restrict__ dst, int swap){
  int idx = blockIdx.x*256 + threadIdx.x;
  if (idx >= 192*10368) return;
  int n = idx / 10368; int k = idx - n*10368;
  int t = k / 384; int c = k - t*384;
  int cs = c + swap; if (cs >= 384) cs -= 384;
  dst[idx] = f2b(src[((size_t)n*384 + cs)*27 + t]);
}
// ------ conv2 weight prep: (96,192,27) f32 -> [n][t*192+c] bf16 ------------
__global__ void k_prepw2b(const float* __restrict__ src, u16* __restrict__ dst){
  int idx = blockIdx.x*256 + threadIdx.x;
  if (idx >= 96*5184) return;
  int n = idx / 5184; int k = idx - n*5184;
  int t = k / 192; int c = k - t*192;
  dst[idx] = f2b(src[((size_t)n*192 + c)*27 + t]);
}
// ------ generic f32 -> bf16 copy (row-major weights) -----------------------
__global__ void k_prepwb(const float* __restrict__ src, u16* __restrict__ dst, int count){
  int idx = blockIdx.x*256 + threadIdx.x;
  if (idx < count) dst[idx] = f2b(src[idx]);
}

// ------ bias matrix prep: [type 8][head 6][key 352][query 352] f32 ---------
__global__ void k_prepbias(const float* __restrict__ rpt, float* __restrict__ bm){
  int idx = blockIdx.x*256 + threadIdx.x;
  if (idx >= 48*123904) return;
  int th = idx / 123904; int r = idx - th*123904;
  int key = r / 352; int q = r - key*352;
  int type = th / 6; int h = th - type*6;
  float v;
  if (key >= 343 || q >= 343){
    v = -30000.f;
  } else {
    int ki = key/49, kj = (key/7)%7, kk = key%7;
    int qi = q/49,   qj = (q/7)%7,   qk = q%7;
    int ridx = ((qi-ki+6)*13 + (qj-kj+6))*13 + (qk-kk+6);
    float rv = rpt[ridx*6 + h];
    int bd = (type>>2)&1, bh = (type>>1)&1, bw = type&1;
    int lq_ = (bd?((qi<4)?1:2):0)*9 + (bh?((qj<4)?1:2):0)*3 + (bw?((qk<4)?1:2):0);
    int lk_ = (bd?((ki<4)?1:2):0)*9 + (bh?((kj<4)?1:2):0)*3 + (bw?((kk<4)?1:2):0);
    v = rv + ((lq_==lk_) ? 0.f : -100.f);
  }
  bm[idx] = v;
}

// ------ padded volume builders (30^3, zero borders), bf16 ------------------
__global__ __launch_bounds__(192) void k_pad1(const float* __restrict__ m_, const float* __restrict__ f_,
                                              u16* __restrict__ xp){
  int p = blockIdx.x; int t = threadIdx.x;
  int pd = p/900; int r = p - pd*900; int ph = r/30; int pw = r - ph*30;
  int d = pd-1, h = ph-1, w = pw-1;
  u16 vm = 0, vf = 0;
  if ((unsigned)d < 28u && (unsigned)h < 28u && (unsigned)w < 28u){
    size_t l = (size_t)((d*28+h)*28+w)*192 + t;
    vm = f2b(m_[l]); vf = f2b(f_[l]);
  }
  xp[(size_t)p*384 + t] = vm;
  xp[(size_t)p*384 + 192 + t] = vf;
}
__global__ __launch_bounds__(192) void k_pad2(const float* __restrict__ t1,
                                              const float* __restrict__ a1, const float* __restrict__ b1,
                                              u16* __restrict__ xp2){
  int p = blockIdx.x; int t = threadIdx.x;
  int pd = p/900; int r = p - pd*900; int ph = r/30; int pw = r - ph*30;
  int d = pd-1, h = ph-1, w = pw-1;
  u16 v = 0;
  if ((unsigned)d < 28u && (unsigned)h < 28u && (unsigned)w < 28u){
    float xv = t1[(size_t)((d*28+h)*28+w)*192 + t];
    v = f2b(fmaxf(xv*a1[t] + b1[t], 0.f));
  }
  xp2[(size_t)p*192 + t] = v;
}

// ------ implicit-GEMM MFMA conv 3x3x3, fused m+f (grid = 2*686 = 1372) -----
// 64-channel K-steps (2 MFMA chunks per barrier), XOR-swizzled LDS (no pad),
// bijective XCD swizzle: m-blocks -> XCD 0-3, f-blocks -> XCD 4-7.
template<int CIN, int COUTB, int COUTF, int NWN>
__global__ __launch_bounds__(256) void k_convmfma(const u16* __restrict__ xpA,
                                                  const u16* __restrict__ xpB,
                                                  const u16* __restrict__ wA,
                                                  const u16* __restrict__ wB,
                                                  float* __restrict__ outA,
                                                  float* __restrict__ outB){
  constexpr int K = 27*CIN;
  constexpr int STEPS = K/64;         // 64 channels per step (CIN%64==0)
  constexpr int MT = (NWN==2)?2:1;
  constexpr int NT = COUTB/16/NWN;
  __shared__ __align__(16) u16 As[2][64*64];
  __shared__ __align__(16) u16 Bs[2][COUTB*64];
  int tid = threadIdx.x;
  int wave = tid>>6, lane = tid&63;
  int lm = lane&15, lq = lane>>4;
  // bijective XCD swizzle over nwg=1372: q=171, r=4
  int b0 = blockIdx.x;
  int xcd = b0 & 7, ii = b0 >> 3;
  int bid = (xcd < 4 ? xcd*172 : 688 + (xcd-4)*171) + ii;
  int which = (bid >= 686) ? 1 : 0;
  int t = bid - which*686;
  const u16* xp  = which ? xpB : xpA;
  const u16* wtb = (which ? wB : wA) + (size_t)((t&1)*COUTB)*K;
  float* out = which ? outB : outA;
  int v0 = (t>>1)*64;
  int ncol0 = (t&1)*COUTB;
  int sv  = tid>>2;                 // staged A row 0..63
  int scb = (tid&3)*16;             // byte offset of 16B chunk within 128B row
  int av = v0 + sv;
  int d = av/784; int rm2 = av - d*784; int hh = rm2/28; int ww = rm2 - hh*28;
  int pbase = (d*30 + hh)*30 + ww;
  int wave_m = (NWN==2) ? (wave>>1) : wave;
  int wave_n = (NWN==2) ? (wave&1) : 0;
  int mbase = wave_m*16*MT;
  int nbase = wave_n*16*NT;

  float4v acc[MT][NT];
  #pragma unroll
  for (int mt=0; mt<MT; mt++)
    #pragma unroll
    for (int nt=0; nt<NT; nt++) acc[mt][nt] = (float4v)0.f;

  auto stage = [&](int buf, int s){
    int kb = s*64;
    int tp = kb/CIN; int c0 = kb - tp*CIN;
    int td = tp/9; int tr = tp - td*9; int th = tr/3; int tw = tr - th*3;
    int toff = td*900 + th*30 + tw;
    const u16* asrc = xp + (size_t)(pbase + toff)*CIN + c0 + (tid&3)*8;
    char* ab = (char*)&As[buf][0] + sv*128;
    int aswz = (sv&7)<<4;
    #pragma unroll
    for (int h2=0; h2<2; h2++){
      uint4 val = *(const uint4*)(asrc + h2*32);
      *(uint4*)(ab + ((scb + h2*64) ^ aswz)) = val;
    }
    for (int bi = tid; bi < COUTB*8; bi += 256){
      int n = bi>>3, ch = bi&7;
      uint4 val = *(const uint4*)(wtb + (size_t)n*K + kb + ch*8);
      *(uint4*)((char*)&Bs[buf][0] + n*128 + ((ch*16) ^ ((n&7)<<4))) = val;
    }
  };

  stage(0, 0);
  __syncthreads();
  for (int s = 0; s < STEPS; s++){
    if (s+1 < STEPS) stage((s+1)&1, s+1);
    int buf = s&1;
    #pragma unroll
    for (int kk=0; kk<2; kk++){
      short8 aa[MT], bfr[NT];
      #pragma unroll
      for (int mt=0; mt<MT; mt++){
        int row = mbase + mt*16 + lm;
        aa[mt] = *(const short8*)((const char*)&As[buf][0] + row*128 + ((kk*64 + lq*16) ^ ((row&7)<<4)));
      }
      #pragma unroll
      for (int nt=0; nt<NT; nt++){
        int n = nbase + nt*16 + lm;
        bfr[nt] = *(const short8*)((const char*)&Bs[buf][0] + n*128 + ((kk*64 + lq*16) ^ ((n&7)<<4)));
      }
      #pragma unroll
      for (int nt=0; nt<NT; nt++)
        #pragma unroll
        for (int mt=0; mt<MT; mt++)
          acc[mt][nt] = __builtin_amdgcn_mfma_f32_16x16x32_bf16(aa[mt], bfr[nt], acc[mt][nt], 0, 0, 0);
    }
    __syncthreads();
  }
  #pragma unroll
  for (int mt=0; mt<MT; mt++)
    #pragma unroll
    for (int nt=0; nt<NT; nt++)
      #pragma unroll
      for (int r=0; r<4; r++){
        int row = v0 + mbase + mt*16 + lq*4 + r;
        int col = ncol0 + nbase + nt*16 + lm;
        out[(size_t)row*COUTF + col] = acc[mt][nt][r];
      }
}

// ---- generic MFMA GEMM: out[M=21952 rows][NF] = A[map(row)][K] * B[NF][K]^T
template<int K, int NF, int GATHER, int ASRC, int EPI>
__global__ __launch_bounds__(256) void k_gemm(const float* __restrict__ Af,
                                              const u16* __restrict__ Ab,
                                              const u16* __restrict__ B,
                                              const float* __restrict__ bias,
                                              const float* __restrict__ resid,
                                              float* __restrict__ outf,
                                              u16* __restrict__ out16,
                                              u16* __restrict__ out16b,
                                              float scale){
  constexpr int STEPS = K/32;
  constexpr int NB = NF/64;
  __shared__ __align__(16) u16 As[2][64*40];
  __shared__ __align__(16) u16 Bs[2][64*40];
  __shared__ int map[64];
  int tid = threadIdx.x;
  int bid = blockIdx.x;
  int mb = bid / NB, nb = bid - mb*NB;
  int v0 = mb*64, ncol0 = nb*64;
  if (tid < 64){
    int r = v0 + tid;
    int src;
    if (GATHER == 0){
      src = r;
    } else if (GATHER == 1){
      int w = r/343; int n = r - w*343;
      int nd = w>>4, nh = (w>>2)&3, nw = w&3;
      int i = n/49; int rr = n - i*49; int j = rr/7; int k2 = rr - j*7;
      int dd = nd*7 + i + 3; if (dd >= 28) dd -= 28;
      int hh = nh*7 + j + 3; if (hh >= 28) hh -= 28;
      int ww = nw*7 + k2 + 3; if (ww >= 28) ww -= 28;
      src = (dd*28 + hh)*28 + ww;
    } else {
      int l = r;
      int d = l/784; int rm = l - d*784; int y = rm/28; int x = rm - y*28;
      int dp = d-3; if (dp<0) dp+=28;
      int yp = y-3; if (yp<0) yp+=28;
      int xq = x-3; if (xq<0) xq+=28;
      int nd = dp/7, i = dp - nd*7;
      int nh = yp/7, j = yp - nh*7;
      int nw = xq/7, k2 = xq - nw*7;
      src = ((nd*4+nh)*4+nw)*NTOK + (i*7+j)*7 + k2;
    }
    map[tid] = src;
  }
  __syncthreads();
  int sv = tid>>2, c8 = (tid&3)*8;
  int lane = tid&63, wv = tid>>6;
  int lm = lane&15, lq = lane>>4;
  int mbase = (wv>>1)*32, nbase = (wv&1)*32;

  float4v acc[2][2];
  #pragma unroll
  for (int mt=0; mt<2; mt++)
    #pragma unroll
    for (int nt=0; nt<2; nt++) acc[mt][nt] = (float4v)0.f;

  auto stage = [&](int buf, int s){
    if (ASRC == 0){
      const float* ap = Af + (size_t)map[sv]*K + s*32 + c8;
      float4 a0 = *(const float4*)ap;
      float4 a1 = *(const float4*)(ap+4);
      uint4 pk;
      pk.x = (u32)f2b(a0.x) | ((u32)f2b(a0.y)<<16);
      pk.y = (u32)f2b(a0.z) | ((u32)f2b(a0.w)<<16);
      pk.z = (u32)f2b(a1.x) | ((u32)f2b(a1.y)<<16);
      pk.w = (u32)f2b(a1.z) | ((u32)f2b(a1.w)<<16);
      *(uint4*)(&As[buf][sv*40 + c8]) = pk;
    } else {
      uint4 val = *(const uint4*)(Ab + (size_t)map[sv]*K + s*32 + c8);
      *(uint4*)(&As[buf][sv*40 + c8]) = val;
    }
    uint4 bv = *(const uint4*)(B + (size_t)(ncol0 + sv)*K + s*32 + c8);
    *(uint4*)(&Bs[buf][sv*40 + c8]) = bv;
  };

  stage(0, 0);
  __syncthreads();
  for (int s = 0; s < STEPS; s++){
    if (s+1 < STEPS) stage((s+1)&1, s+1);
    int buf = s&1;
    short8 aa[2], bb[2];
    #pragma unroll
    for (int mt=0; mt<2; mt++)
      aa[mt] = *(const short8*)(&As[buf][(mbase + mt*16 + lm)*40 + lq*8]);
    #pragma unroll
    for (int nt=0; nt<2; nt++)
      bb[nt] = *(const short8*)(&Bs[buf][(nbase + nt*16 + lm)*40 + lq*8]);
    #pragma unroll
    for (int nt=0; nt<2; nt++)
      #pragma unroll
      for (int mt=0; mt<2; mt++)
        acc[mt][nt] = __builtin_amdgcn_mfma_f32_16x16x32_bf16(aa[mt], bb[nt], acc[mt][nt], 0, 0, 0);
    __syncthreads();
  }
  // epilogue
  float bv[2];
  #pragma unroll
  for (int nt=0; nt<2; nt++) bv[nt] = bias ? bias[ncol0 + nbase + nt*16 + lm] : 0.f;
  #pragma unroll
  for (int mt=0; mt<2; mt++){
    #pragma unroll
    for (int r=0; r<4; r++){
      int row = v0 + mbase + mt*16 + lq*4 + r;
      if (EPI == 0 || EPI == 3){
        int w = row/343; int tok = row - w*343;
        #pragma unroll
        for (int nt=0; nt<2; nt++){
          int col = ncol0 + nbase + nt*16 + lm;
          float val = (acc[mt][nt][r] + bv[nt]) * scale;
          if (EPI == 0){
            int h = col>>5, c = col&31;
            out16[((size_t)(w*6 + h)*343 + tok)*32 + c] = f2b(val);
          } else {
            u16* dst = (col < 192) ? out16 : out16b;
            int cc = (col < 192) ? col : col - 192;
            int h = cc>>5, c = cc&31;
            dst[((size_t)(w*6 + h)*343 + tok)*32 + c] = f2b(val);
          }
        }
      } else if (EPI == 1){
        #pragma unroll
        for (int nt=0; nt<2; nt++){
          int col = ncol0 + nbase + nt*16 + lm;
          size_t o = (size_t)row*NF + col;
          outf[o] = acc[mt][nt][r] + bv[nt] + resid[o];
        }
      } else {
        #pragma unroll
        for (int nt=0; nt<2; nt++){
          int col = ncol0 + nbase + nt*16 + lm;
          float v = acc[mt][nt][r] + bv[nt];
          float gl = 0.5f*v*(1.f + erff(v*0.70710678118f));
          out16[(size_t)row*NF + col] = f2b(gl);
        }
      }
    }
  }
}

// ---- BN stats, coalesced 2-stage: partial sums then finalize --------------
__global__ __launch_bounds__(192) void k_bnsum(const float* __restrict__ x, int C,
                                               float* __restrict__ psum){
  int bid = blockIdx.x, t = threadIdx.x;
  int rpi = 192/C;
  int c  = (C==192) ? t : (t % 96);
  int ro = (C==192) ? 0 : (t / 96);
  float s=0.f, s2=0.f;
  int base = bid*343;
  for (int r = ro; r < 343; r += rpi){
    float v = x[(size_t)(base+r)*C + c];
    s += v; s2 += v*v;
  }
  psum[(size_t)bid*384 + t]       = s;
  psum[(size_t)bid*384 + 192 + t] = s2;
}
__global__ void k_bnfin(const float* __restrict__ psum, int C,
                        const float* __restrict__ g, const float* __restrict__ b,
                        float* __restrict__ a_out, float* __restrict__ b_out){
  int c = threadIdx.x;
  if (c >= C) return;
  int slots = 192/C;
  float s=0.f, s2=0.f;
  for (int bb=0; bb<64; bb++)
    for (int k=0; k<slots; k++){
      s  += psum[(size_t)bb*384 + k*C + c];
      s2 += psum[(size_t)bb*384 + 192 + k*C + c];
    }
  float mu = s/(float)LTOT;
  float var = s2/(float)LTOT - mu*mu;
  float rstd = rsqrtf(var + 1e-5f);
  float aa = rstd * g[c];
  a_out[c] = aa;
  b_out[c] = b[c] - mu*aa;
}

// ------------- conv3 1x1x1: 96 -> 18 flow channels, layout (18, L) ---------
__global__ __launch_bounds__(96) void k_flow(const float* __restrict__ t2,
                                             const float* __restrict__ a2, const float* __restrict__ b2,
                                             const float* __restrict__ w3, float* __restrict__ flow){
  __shared__ float xr[96];
  int l = blockIdx.x; int t = threadIdx.x;
  float xv = t2[(size_t)l*96 + t];
  xr[t] = fmaxf(xv*a2[t] + b2[t], 0.f);
  __syncthreads();
  if (t < 18){
    float acc = 0.f;
    for (int c=0;c<96;c++) acc += xr[c]*w3[t*96 + c];
    flow[(size_t)t*LTOT + l] = acc;
  }
}

// ------------- trilinear warp (per-head flow), border clamp ----------------
__global__ __launch_bounds__(192) void k_warp(const float* __restrict__ src,
                                              const float* __restrict__ flow, float* __restrict__ dst){
  int l = blockIdx.x; int tid = threadIdx.x; int hh = tid>>5;
  int d = l/784; int rm = l - d*784; int y = rm/28; int x = rm - y*28;
  float fd = flow[(size_t)(hh*3+0)*LTOT + l];
  float fy = flow[(size_t)(hh*3+1)*LTOT + l];
  float fx = flow[(size_t)(hh*3+2)*LTOT + l];
  float cd = fminf(fmaxf((float)d + fd, 0.f), 27.f);
  float cy = fminf(fmaxf((float)y + fy, 0.f), 27.f);
  float cx = fminf(fmaxf((float)x + fx, 0.f), 27.f);
  int d0 = (int)floorf(cd); int d1 = min(d0+1, 27);
  int y0 = (int)floorf(cy); int y1 = min(y0+1, 27);
  int x0 = (int)floorf(cx); int x1 = min(x0+1, 27);
  float wd = cd - (float)d0, wy = cy - (float)y0, wx = cx - (float)x0;
  #define SMP(di,yi,xi) src[(size_t)(((di)*28+(yi))*28+(xi))*192 + tid]
  float v000 = SMP(d0,y0,x0), v001 = SMP(d0,y0,x1), v010 = SMP(d0,y1,x0), v011 = SMP(d0,y1,x1);
  float v100 = SMP(d1,y0,x0), v101 = SMP(d1,y0,x1), v110 = SMP(d1,y1,x0), v111 = SMP(d1,y1,x1);
  #undef SMP
  float o = v000*(1-wd)*(1-wy)*(1-wx) + v001*(1-wd)*(1-wy)*wx
          + v010*(1-wd)*wy*(1-wx)     + v011*(1-wd)*wy*wx
          + v100*wd*(1-wy)*(1-wx)     + v101*wd*(1-wy)*wx
          + v110*wd*wy*(1-wx)         + v111*wd*wy*wx;
  dst[(size_t)l*192 + tid] = o;
}

// ------------ MFMA attention: block = (window, head, q-group) --------------
__global__ __launch_bounds__(256) void k_attmfma(const u16* __restrict__ Q,
                                                 const u16* __restrict__ K,
                                                 const u16* __restrict__ V,
                                                 const float* __restrict__ bm,
                                                 float* __restrict__ ctx){
  __shared__ __align__(16) u16 Kl[352*40];      // [key][40]
  __shared__ __align__(16) u16 Vt[32*360];      // [dim][360]
  __shared__ __align__(16) u16 Pl[4][2][16*40]; // per-wave, dbuf
  int bid = blockIdx.x;
  int wh = bid/6, qg = bid - (bid/6)*6;
  int w = wh/6, h = wh - w*6;
  int tid = threadIdx.x;
  int nd = w>>4, nh = (w>>2)&3, nw = w&3;
  int type = ((nd==3)?4:0) | ((nh==3)?2:0) | ((nw==3)?1:0);
  const u16* kb = K + (size_t)wh*10976;
  const u16* vbp = V + (size_t)wh*10976;
  for (int idx=tid; idx<343*4; idx+=256){
    int row = idx>>2, c8 = (idx&3)*8;
    uint4 val = *(const uint4*)(kb + row*32 + c8);
    *(uint4*)(&Kl[row*40 + c8]) = val;
  }
  for (int idx=tid; idx<9*40; idx+=256) Kl[343*40 + idx] = 0;
  for (int idx=tid; idx<343*4; idx+=256){
    int row = idx>>2, c8 = (idx&3)*8;
    uint4 val = *(const uint4*)(vbp + row*32 + c8);
    const u16* pv = (const u16*)&val;
    #pragma unroll
    for (int j=0;j<8;j++) Vt[(c8+j)*360 + row] = pv[j];
  }
  for (int idx=tid; idx<32*17; idx+=256){
    int dd = idx/17, cc = 343 + idx - (idx/17)*17;
    Vt[dd*360 + cc] = 0;
  }
  __syncthreads();
  int lane = tid&63, wv = tid>>6;
  int lm = lane&15, lq = lane>>4;
  const float* bmh = bm + (size_t)(type*6 + h)*123904;
  int qt = qg*4 + wv;
  if (qt < 22){
    int q0 = qt*16;
    short8 bq = *(const short8*)(Q + (size_t)wh*10976 + (q0+lm)*32 + lq*8);
    float4v sc[22];
    #pragma unroll
    for (int kt=0; kt<22; kt++){
      short8 ak = *(const short8*)(&Kl[(kt*16+lm)*40 + lq*8]);
      sc[kt] = __builtin_amdgcn_mfma_f32_16x16x32_bf16(ak, bq, (float4v)0.f, 0, 0, 0);
    }
    const float* bcol = bmh + q0 + lm;
    float mx = -3.0e38f;
    #pragma unroll
    for (int kt=0; kt<22; kt++){
      #pragma unroll
      for (int r=0; r<4; r++){
        int key = kt*16 + lq*4 + r;
        float s = sc[kt][r] + bcol[(size_t)key*352];
        sc[kt][r] = s;
        mx = fmaxf(mx, s);
      }
    }
    mx = fmaxf(mx, __shfl_xor(mx, 16));
    mx = fmaxf(mx, __shfl_xor(mx, 32));
    float sm = 0.f;
    #pragma unroll
    for (int kt=0; kt<22; kt++){
      #pragma unroll
      for (int r=0; r<4; r++){
        float p = __expf(sc[kt][r] - mx);
        sc[kt][r] = p;
        sm += p;
      }
    }
    sm += __shfl_xor(sm, 16);
    sm += __shfl_xor(sm, 32);
    float inv = 1.f/sm;
    float4v o0 = (float4v)0.f, o1 = (float4v)0.f;
    #pragma unroll
    for (int s=0; s<11; s++){
      u16* pw = &Pl[wv][s&1][0];
      #pragma unroll
      for (int half=0; half<2; half++){
        int kt = 2*s + half;
        uint2 pv2;
        pv2.x = (u32)f2b(sc[kt][0]) | ((u32)f2b(sc[kt][1])<<16);
        pv2.y = (u32)f2b(sc[kt][2]) | ((u32)f2b(sc[kt][3])<<16);
        *(uint2*)(&pw[lm*40 + half*16 + lq*4]) = pv2;
      }
      short8 bp = *(const short8*)(&pw[lm*40 + lq*8]);
      short8 a0 = *(const short8*)(&Vt[lm*360 + s*32 + lq*8]);
      short8 a1 = *(const short8*)(&Vt[(16+lm)*360 + s*32 + lq*8]);
      o0 = __builtin_amdgcn_mfma_f32_16x16x32_bf16(a0, bp, o0, 0, 0, 0);
      o1 = __builtin_amdgcn_mfma_f32_16x16x32_bf16(a1, bp, o1, 0, 0, 0);
    }
    int query = q0 + lm;
    if (query < 343){
      float* ob = ctx + ((size_t)w*NTOK + query)*192 + h*32;
      float4 t0, t1v;
      t0.x = o0[0]*inv; t0.y = o0[1]*inv; t0.z = o0[2]*inv; t0.w = o0[3]*inv;
      t1v.x = o1[0]*inv; t1v.y = o1[1]*inv; t1v.z = o1[2]*inv; t1v.w = o1[3]*inv;
      *(float4*)(ob + lq*4) = t0;
      *(float4*)(ob + 16 + lq*4) = t1v;
    }
  }
}

// ===========================================================================
extern "C" void kernel_launch(void* const* d_in, const int* in_sizes, int n_in,
                              void* d_out, int out_size, void* d_ws, size_t ws_size,
                              hipStream_t stream){
  const float* mov     = (const float*)d_in[0];
  const float* fix     = (const float*)d_in[1];
  const float* n1g     = (const float*)d_in[2];
  const float* n1b     = (const float*)d_in[3];
  const float* offm_w1 = (const float*)d_in[4];
  const float* offm_g1 = (const float*)d_in[5];
  const float* offm_b1 = (const float*)d_in[6];
  const float* offm_w2 = (const float*)d_in[7];
  const float* offm_g2 = (const float*)d_in[8];
  const float* offm_b2 = (const float*)d_in[9];
  const float* offm_w3 = (const float*)d_in[10];
  const float* offf_w1 = (const float*)d_in[11];
  const float* offf_g1 = (const float*)d_in[12];
  const float* offf_b1 = (const float*)d_in[13];
  const float* offf_w2 = (const float*)d_in[14];
  const float* offf_g2 = (const float*)d_in[15];
  const float* offf_b2 = (const float*)d_in[16];
  const float* offf_w3 = (const float*)d_in[17];
  const float* mq_w    = (const float*)d_in[18];
  const float* mkv_w   = (const float*)d_in[19];
  const float* fq_w    = (const float*)d_in[20];
  const float* fkv_w   = (const float*)d_in[21];
  const float* mproj_w = (const float*)d_in[22];
  const float* fproj_w = (const float*)d_in[23];
  const float* mq_b    = (const float*)d_in[24];
  const float* mkv_b   = (const float*)d_in[25];
  const float* fq_b    = (const float*)d_in[26];
  const float* fkv_b   = (const float*)d_in[27];
  const float* mproj_b = (const float*)d_in[28];
  const float* fproj_b = (const float*)d_in[29];
  const float* rpbt    = (const float*)d_in[30];
  const float* n2g     = (const float*)d_in[31];
  const float* n2b     = (const float*)d_in[32];
  const float* fc1_w   = (const float*)d_in[33];
  const float* fc1_b   = (const float*)d_in[34];
  const float* fc2_w   = (const float*)d_in[35];
  const float* fc2_b   = (const float*)d_in[36];
  float* outp = (float*)d_out;

  float* W = (float*)d_ws;
  const size_t L192 = (size_t)LTOT*192;   // floats per region (16.86 MB)
  // conv-phase layout (no overlaps; fixes old xp2/a1v race):
  float* m_   = W;                         // region 0
  float* f_   = W + 1*L192;                // region 1
  float* t1m  = W + 2*L192;                // region 2
  float* t1f  = W + 3*L192;                // region 3
  u16* xp     = (u16*)(W + 4*L192);        // 20.74 MB (region 4 + head of 5)
  u16* xp2m   = xp + (size_t)27000*384;    // 10.37 MB (inside region 5)
  u16* xp2f   = (u16*)(W + 6*L192);        // 10.37 MB (head of region 6)
  float* sb   = W + 6*L192 + 3000000;      // stats block (region 6 + 12 MB)
  float* a1m = sb,       *b1m = sb+192;
  float* a1f = sb+384,   *b1f = sb+576;
  float* a2m = sb+768,   *b2m = sb+864;
  float* a2f = sb+960,   *b2f = sb+1056;
  float* psum = sb + 1152;                 // 64*384 floats
  float* flowm = W + 6*L192 + 3100000;     // region 6 + 12.4 MB
  float* flowf = flowm + (size_t)LTOT*18;
  float* t2m  = W + 7*L192;                // region 7 first half
  float* t2f  = W + 7*L192 + (size_t)LTOT*96;  // region 7 second half
  u16* wt1m = (u16*)(W + 8*L192);          // conv weights, region 8
  u16* wt1f = wt1m + 192*10368;
  u16* wt2m = wt1f + 192*10368;
  u16* wt2f = wt2m + 96*5184;
  // post-conv reuse (same as before):
  float* dmov = W + 4*L192;
  float* dfix = W + 5*L192;
  float* ctxm = dmov; float* ctxf = dfix;
  float* mout = m_;   float* fout = f_;
  u16* QMb = (u16*)(W + 6*L192);
  u16* QFb = (u16*)(W + 7*L192);
  u16* Kmb = (u16*)(W + 2*L192);
  u16* Vmb = (u16*)(W + 3*L192);
  u16* Kfb = (u16*)(W + 8*L192);
  u16* Vfb = (u16*)(W + 9*L192);
  float* bm = W;
  u16* wq_m  = (u16*)(W + 9*L192) + 4214784;
  u16* wq_f  = wq_m  + 36864;
  u16* wkv_m = wq_f  + 36864;
  u16* wkv_f = wkv_m + 73728;
  u16* wpj_m = wkv_f + 73728;
  u16* wpj_f = wpj_m + 36864;
  u16* wfc1  = wpj_f + 36864;
  u16* wfc2  = wfc1  + 147456;
  u16* hs16  = (u16*)(W + 2*L192);
  float* lnbuf = W + 6*L192;

  // conv weight prep
  k_prepw1b<<<(192*10368+255)/256, 256, 0, stream>>>(offm_w1, wt1m, 0);
  k_prepw1b<<<(192*10368+255)/256, 256, 0, stream>>>(offf_w1, wt1f, 192);
  k_prepw2b<<<(96*5184+255)/256, 256, 0, stream>>>(offm_w2, wt2m);
  k_prepw2b<<<(96*5184+255)/256, 256, 0, stream>>>(offf_w2, wt2f);
  // GEMM weight prep (f32 -> bf16, same layout)
  k_prepwb<<<144, 256, 0, stream>>>(mq_w,    wq_m,  36864);
  k_prepwb<<<144, 256, 0, stream>>>(fq_w,    wq_f,  36864);
  k_prepwb<<<288, 256, 0, stream>>>(mkv_w,   wkv_m, 73728);
  k_prepwb<<<288, 256, 0, stream>>>(fkv_w,   wkv_f, 73728);
  k_prepwb<<<144, 256, 0, stream>>>(mproj_w, wpj_m, 36864);
  k_prepwb<<<144, 256, 0, stream>>>(fproj_w, wpj_f, 36864);
  k_prepwb<<<576, 256, 0, stream>>>(fc1_w,   wfc1,  147456);
  k_prepwb<<<576, 256, 0, stream>>>(fc2_w,   wfc2,  147456);
  // layernorm1
  k_ln<<<2*LTOT, 64, 0, stream>>>(mov, fix, n1g, n1b, m_, f_);
  // padded bf16 volume [m|f]
  k_pad1<<<27000, 192, 0, stream>>>(m_, f_, xp);
  // offset block conv1: m+f fused in one launch (grid 1372)
  k_convmfma<384,96,192,2><<<1372, 256, 0, stream>>>(xp, xp, wt1m, wt1f, t1m, t1f);
  k_bnsum<<<64, 192, 0, stream>>>(t1m, 192, psum);
  k_bnfin<<<1, 192, 0, stream>>>(psum, 192, offm_g1, offm_b1, a1m, b1m);
  k_bnsum<<<64, 192, 0, stream>>>(t1f, 192, psum);
  k_bnfin<<<1, 192, 0, stream>>>(psum, 192, offf_g1, offf_b1, a1f, b1f);
  k_pad2<<<27000, 192, 0, stream>>>(t1m, a1m, b1m, xp2m);
  k_pad2<<<27000, 192, 0, stream>>>(t1f, a1f, b1f, xp2f);
  // conv2: m+f fused
  k_convmfma<192,48,96,1><<<1372, 256, 0, stream>>>(xp2m, xp2f, wt2m, wt2f, t2m, t2f);
  k_bnsum<<<64, 192, 0, stream>>>(t2m, 96, psum);
  k_bnfin<<<1, 96, 0, stream>>>(psum, 96, offm_g2, offm_b2, a2m, b2m);
  k_bnsum<<<64, 192, 0, stream>>>(t2f, 96, psum);
  k_bnfin<<<1, 96, 0, stream>>>(psum, 96, offf_g2, offf_b2, a2f, b2f);
  k_flow<<<LTOT, 96, 0, stream>>>(t2m, a2m, b2m, offm_w3, flowm);
  k_flow<<<LTOT, 96, 0, stream>>>(t2f, a2f, b2f, offf_w3, flowf);
  // deformable warp
  k_warp<<<LTOT, 192, 0, stream>>>(m_, flowm, dmov);
  k_warp<<<LTOT, 192, 0, stream>>>(f_, flowf, dfix);
  // windowed projections (MFMA GEMM, gather folded into A-map) -> bf16
  const float scale = 0.17677669529663687f; // 32^-0.5
  k_gemm<192,192,1,0,0><<<343*3, 256, 0, stream>>>(dmov, nullptr, wq_m,  mq_b,  nullptr, nullptr, QMb, nullptr, scale);
  k_gemm<192,192,1,0,0><<<343*3, 256, 0, stream>>>(dfix, nullptr, wq_f,  fq_b,  nullptr, nullptr, QFb, nullptr, scale);
  k_gemm<192,384,1,0,3><<<343*6, 256, 0, stream>>>(m_,   nullptr, wkv_m, mkv_b, nullptr, nullptr, Kmb, Vmb, 1.f);
  k_gemm<192,384,1,0,3><<<343*6, 256, 0, stream>>>(f_,   nullptr, wkv_f, fkv_b, nullptr, nullptr, Kfb, Vfb, 1.f);
  // bias matrix (m_/f_ now dead)
  k_prepbias<<<(48*123904+255)/256, 256, 0, stream>>>(rpbt, bm);
  // attention: mo = attend(dfQ, mK, mV); fo = attend(dmQ, fK, fV)
  k_attmfma<<<2304, 256, 0, stream>>>(QFb, Kmb, Vmb, bm, ctxm);
  k_attmfma<<<2304, 256, 0, stream>>>(QMb, Kfb, Vfb, bm, ctxf);
  // proj + residual + window-reverse (gather on A rows)
  k_gemm<192,192,2,0,1><<<343*3, 256, 0, stream>>>(ctxm, nullptr, wpj_m, mproj_b, mov, mout, nullptr, nullptr, 1.f);
  k_gemm<192,192,2,0,1><<<343*3, 256, 0, stream>>>(ctxf, nullptr, wpj_f, fproj_b, fix, fout, nullptr, nullptr, 1.f);
  // MLP (mov half): LN -> fc1(gelu, bf16 hs) -> fc2(+resid)
  k_ln1<<<LTOT, 64, 0, stream>>>(mout, n2g, n2b, lnbuf);
  k_gemm<192,768,0,0,2><<<343*12, 256, 0, stream>>>(lnbuf, nullptr, wfc1, fc1_b, nullptr, nullptr, hs16, nullptr, 1.f);
  k_gemm<768,192,0,1,1><<<343*3, 256, 0, stream>>>(nullptr, hs16, wfc2, fc2_b, mout, outp, nullptr, nullptr, 1.f);
  // MLP (fix half)
  k_ln1<<<LTOT, 64, 0, stream>>>(fout, n2g, n2b, lnbuf);
  k_gemm<192,768,0,0,2><<<343*12, 256, 0, stream>>>(lnbuf, nullptr, wfc1, fc1_b, nullptr, nullptr, hs16, nullptr, 1.f);
  k_gemm<768,192,0,1,1><<<343*3, 256, 0, stream>>>(nullptr, hs16, wfc2, fc2_b, fout, outp + L192, nullptr, nullptr, 1.f);
}

// Round 2
// 1442.535 us; speedup vs baseline: 1.2527x; 1.1728x over previous
//
#include <hip/hip_runtime.h>

#define LTOT 21952      // 28^3
#define NTOK 343        // 7^3

typedef unsigned short u16;
typedef unsigned int   u32;
typedef __attribute__((ext_vector_type(8))) short short8;
typedef __attribute__((ext_vector_type(4))) float float4v;

__device__ __forceinline__ u16 f2b(float f){
  u32 x = __float_as_uint(f);
  u32 r = (x + 0x7fffu + ((x>>16)&1u)) >> 16;
  return (u16)r;
}

// ---------------- LayerNorm (norm1) : f32 in -> f32 out --------------------
__global__ __launch_bounds__(64) void k_ln(const float* __restrict__ mov, const float* __restrict__ fix,
                                           const float* __restrict__ g, const float* __restrict__ b,
                                           float* __restrict__ om, float* __restrict__ of){
  int row = blockIdx.x;
  const float* src; float* dst;
  if (row < LTOT){ src = mov + (size_t)row*192; dst = om + (size_t)row*192; }
  else          { src = fix + (size_t)(row-LTOT)*192; dst = of + (size_t)(row-LTOT)*192; }
  int t = threadIdx.x;
  float x0 = src[t], x1 = src[t+64], x2 = src[t+128];
  float s = x0+x1+x2, s2 = x0*x0 + x1*x1 + x2*x2;
  for (int o=32;o;o>>=1){ s += __shfl_xor(s,o); s2 += __shfl_xor(s2,o); }
  float mu = s*(1.f/192.f);
  float var = s2*(1.f/192.f) - mu*mu;
  float rs = rsqrtf(var + 1e-5f);
  dst[t]     = (x0-mu)*rs*g[t]     + b[t];
  dst[t+64]  = (x1-mu)*rs*g[t+64]  + b[t+64];
  dst[t+128] = (x2-mu)*rs*g[t+128] + b[t+128];
}

// ---------------- LayerNorm (norm2), single buffer -------------------------
__global__ __launch_bounds__(64) void k_ln1(const float* __restrict__ x,
                                            const float* __restrict__ g, const float* __restrict__ b,
                                            float* __restrict__ y){
  int row = blockIdx.x;
  const float* src = x + (size_t)row*192;
  float* dst = y + (size_t)row*192;
  int t = threadIdx.x;
  float x0 = src[t], x1 = src[t+64], x2 = src[t+128];
  float s = x0+x1+x2, s2 = x0*x0 + x1*x1 + x2*x2;
  for (int o=32;o;o>>=1){ s += __shfl_xor(s,o); s2 += __shfl_xor(s2,o); }
  float mu = s*(1.f/192.f);
  float var = s2*(1.f/192.f) - mu*mu;
  float rs = rsqrtf(var + 1e-5f);
  dst[t]     = (x0-mu)*rs*g[t]     + b[t];
  dst[t+64]  = (x1-mu)*rs*g[t+64]  + b[t+64];
  dst[t+128] = (x2-mu)*rs*g[t+128] + b[t+128];
}

// ------ conv1 weight prep: (192,384,27) f32 -> [n][t*384+c] bf16 -----------
__global__ void k_prepw1b(const float* __restrict__ src, u16* __restrict__ dst, int swap){
  int idx = blockIdx.x*256 + threadIdx.x;
  if (idx >= 192*10368) return;
  int n = idx / 10368; int k = idx - n*10368;
  int t = k / 384; int c = k - t*384;
  int cs = c + swap; if (cs >= 384) cs -= 384;
  dst[idx] = f2b(src[((size_t)n*384 + cs)*27 + t]);
}
// ------ conv2 weight prep: (96,192,27) f32 -> [n][t*192+c] bf16 ------------
__global__ void k_prepw2b(const float* __restrict__ src, u16* __restrict__ dst){
  int idx = blockIdx.x*256 + threadIdx.x;
  if (idx >= 96*5184) return;
  int n = idx / 5184; int k = idx - n*5184;
  int t = k / 192; int c = k - t*192;
  dst[idx] = f2b(src[((size_t)n*192 + c)*27 + t]);
}
// ------ generic f32 -> bf16 copy (row-major weights) -----------------------
__global__ void k_prepwb(const float* __restrict__ src, u16* __restrict__ dst, int count){
  int idx = blockIdx.x*256 + threadIdx.x;
  if (idx < count) dst[idx] = f2b(src[idx]);
}

// ------ bias matrix prep: [type 8][head 6][key 352][query 352] f32 ---------
__global__ void k_prepbias(const float* __restrict__ rpt, float* __restrict__ bm){
  int idx = blockIdx.x*256 + threadIdx.x;
  if (idx >= 48*123904) return;
  int th = idx / 123904; int r = idx - th*123904;
  int key = r / 352; int q = r - key*352;
  int type = th / 6; int h = th - type*6;
  float v;
  if (key >= 343 || q >= 343){
    v = -30000.f;
  } else {
    int ki = key/49, kj = (key/7)%7, kk = key%7;
    int qi = q/49,   qj = (q/7)%7,   qk = q%7;
    int ridx = ((qi-ki+6)*13 + (qj-kj+6))*13 + (qk-kk+6);
    float rv = rpt[ridx*6 + h];
    int bd = (type>>2)&1, bh = (type>>1)&1, bw = type&1;
    int lq_ = (bd?((qi<4)?1:2):0)*9 + (bh?((qj<4)?1:2):0)*3 + (bw?((qk<4)?1:2):0);
    int lk_ = (bd?((ki<4)?1:2):0)*9 + (bh?((kj<4)?1:2):0)*3 + (bw?((kk<4)?1:2):0);
    v = rv + ((lq_==lk_) ? 0.f : -100.f);
  }
  bm[idx] = v;
}

// ------ padded volume builders (30^3, zero borders), bf16 ------------------
__global__ __launch_bounds__(192) void k_pad1(const float* __restrict__ m_, const float* __restrict__ f_,
                                              u16* __restrict__ xp){
  int p = blockIdx.x; int t = threadIdx.x;
  int pd = p/900; int r = p - pd*900; int ph = r/30; int pw = r - ph*30;
  int d = pd-1, h = ph-1, w = pw-1;
  u16 vm = 0, vf = 0;
  if ((unsigned)d < 28u && (unsigned)h < 28u && (unsigned)w < 28u){
    size_t l = (size_t)((d*28+h)*28+w)*192 + t;
    vm = f2b(m_[l]); vf = f2b(f_[l]);
  }
  xp[(size_t)p*384 + t] = vm;
  xp[(size_t)p*384 + 192 + t] = vf;
}
__global__ __launch_bounds__(192) void k_pad2(const float* __restrict__ t1,
                                              const float* __restrict__ a1, const float* __restrict__ b1,
                                              u16* __restrict__ xp2){
  int p = blockIdx.x; int t = threadIdx.x;
  int pd = p/900; int r = p - pd*900; int ph = r/30; int pw = r - ph*30;
  int d = pd-1, h = ph-1, w = pw-1;
  u16 v = 0;
  if ((unsigned)d < 28u && (unsigned)h < 28u && (unsigned)w < 28u){
    float xv = t1[(size_t)((d*28+h)*28+w)*192 + t];
    v = f2b(fmaxf(xv*a1[t] + b1[t], 0.f));
  }
  xp2[(size_t)p*192 + t] = v;
}

// ------ implicit-GEMM MFMA conv 3x3x3, fused m+f (grid = 2*343 = 686) ------
// Full-N blocks (64 x COUT), wave = 32 x COUT/2 (MT=2, NT=COUT/32).
// K-step = 32, 80-byte LDS row stride (2-way-free banks), async-STAGE split:
// loads -> regs before MFMA cluster, ds_write after.  Bijective XCD swizzle.
template<int CIN, int COUT>
__global__ __launch_bounds__(256, 4) void k_convmfma(const u16* __restrict__ xpA,
                                                     const u16* __restrict__ xpB,
                                                     const u16* __restrict__ wA,
                                                     const u16* __restrict__ wB,
                                                     float* __restrict__ outA,
                                                     float* __restrict__ outB){
  constexpr int K = 27*CIN;
  constexpr int CH = CIN/32;          // k-chunks per tap
  constexpr int STEPS = 27*CH;
  constexpr int NT = COUT/32;         // n-tiles per wave (conv1:6, conv2:3)
  constexpr int NB8 = COUT/32;        // B 8B-chunks per thread
  __shared__ __align__(16) u16 As[2][64*40];
  __shared__ __align__(16) u16 Bs[2][COUT*40];
  int tid = threadIdx.x;
  // bijective XCD swizzle over nwg=686: q=85, r=6
  int b0 = blockIdx.x;
  int xcd = b0 & 7, ii = b0 >> 3;
  int bid = (xcd < 6 ? xcd*86 : 516 + (xcd-6)*85) + ii;
  int which = (bid >= 343) ? 1 : 0;
  int t = bid - which*343;
  const u16* xp  = which ? xpB : xpA;
  const u16* wtb = which ? wB : wA;
  float* out = which ? outB : outA;
  int v0 = t*64;
  int sv  = tid>>2;                 // staged A row 0..63
  int c8u = (tid&3)*8;              // u16 offset of 16B chunk
  int av = v0 + sv;
  int d = av/784; int rm2 = av - d*784; int hh = rm2/28; int ww = rm2 - hh*28;
  int pbase = (d*30 + hh)*30 + ww;
  int lane = tid&63, wv = tid>>6;
  int lm = lane&15, lq = lane>>4;
  int mbase = (wv>>1)*32;
  int nbase = (wv&1)*(COUT/2);

  float4v acc[2][NT];
  #pragma unroll
  for (int mt=0; mt<2; mt++)
    #pragma unroll
    for (int nt=0; nt<NT; nt++) acc[mt][nt] = (float4v)0.f;

  uint4 a_r;
  uint2 b_r[NB8];
  auto load_s = [&](int s){
    int tp = s/CH, cc = s - tp*CH;
    int td = tp/9, tr = tp - td*9, th = tr/3, tw = tr - th*3;
    int toff = td*900 + th*30 + tw;
    a_r = *(const uint4*)(xp + (size_t)(pbase + toff)*CIN + cc*32 + c8u);
    #pragma unroll
    for (int j=0;j<NB8;j++){
      int bi = tid + j*256;
      int n = bi>>3, c4 = (bi&7)*4;
      b_r[j] = *(const uint2*)(wtb + (size_t)n*K + s*32 + c4);
    }
  };
  auto write_s = [&](int buf){
    *(uint4*)(&As[buf][sv*40 + c8u]) = a_r;
    #pragma unroll
    for (int j=0;j<NB8;j++){
      int bi = tid + j*256;
      int n = bi>>3, c4 = (bi&7)*4;
      *(uint2*)(&Bs[buf][n*40 + c4]) = b_r[j];
    }
  };

  load_s(0);
  write_s(0);
  __syncthreads();
  for (int s = 0; s < STEPS; s++){
    if (s+1 < STEPS) load_s(s+1);     // issue global loads early
    int buf = s&1;
    short8 aa[2], bb[NT];
    #pragma unroll
    for (int mt=0; mt<2; mt++)
      aa[mt] = *(const short8*)(&As[buf][(mbase + mt*16 + lm)*40 + lq*8]);
    #pragma unroll
    for (int nt=0; nt<NT; nt++)
      bb[nt] = *(const short8*)(&Bs[buf][(nbase + nt*16 + lm)*40 + lq*8]);
    #pragma unroll
    for (int nt=0; nt<NT; nt++)
      #pragma unroll
      for (int mt=0; mt<2; mt++)
        acc[mt][nt] = __builtin_amdgcn_mfma_f32_16x16x32_bf16(aa[mt], bb[nt], acc[mt][nt], 0, 0, 0);
    if (s+1 < STEPS) write_s((s+1)&1);  // drain loads + LDS write after MFMA
    __syncthreads();
  }
  #pragma unroll
  for (int mt=0; mt<2; mt++)
    #pragma unroll
    for (int nt=0; nt<NT; nt++)
      #pragma unroll
      for (int r=0; r<4; r++){
        int row = v0 + mbase + mt*16 + lq*4 + r;
        int col = nbase + nt*16 + lm;
        out[(size_t)row*COUT + col] = acc[mt][nt][r];
      }
}

// ---- generic MFMA GEMM: out[M=21952 rows][NF] = A[map(row)][K] * B[NF][K]^T
template<int K, int NF, int GATHER, int ASRC, int EPI>
__global__ __launch_bounds__(256) void k_gemm(const float* __restrict__ Af,
                                              const u16* __restrict__ Ab,
                                              const u16* __restrict__ B,
                                              const float* __restrict__ bias,
                                              const float* __restrict__ resid,
                                              float* __restrict__ outf,
                                              u16* __restrict__ out16,
                                              u16* __restrict__ out16b,
                                              float scale){
  constexpr int STEPS = K/32;
  constexpr int NB = NF/64;
  __shared__ __align__(16) u16 As[2][64*40];
  __shared__ __align__(16) u16 Bs[2][64*40];
  __shared__ int map[64];
  int tid = threadIdx.x;
  int bid = blockIdx.x;
  int mb = bid / NB, nb = bid - mb*NB;
  int v0 = mb*64, ncol0 = nb*64;
  if (tid < 64){
    int r = v0 + tid;
    int src;
    if (GATHER == 0){
      src = r;
    } else if (GATHER == 1){
      int w = r/343; int n = r - w*343;
      int nd = w>>4, nh = (w>>2)&3, nw = w&3;
      int i = n/49; int rr = n - i*49; int j = rr/7; int k2 = rr - j*7;
      int dd = nd*7 + i + 3; if (dd >= 28) dd -= 28;
      int hh = nh*7 + j + 3; if (hh >= 28) hh -= 28;
      int ww = nw*7 + k2 + 3; if (ww >= 28) ww -= 28;
      src = (dd*28 + hh)*28 + ww;
    } else {
      int l = r;
      int d = l/784; int rm = l - d*784; int y = rm/28; int x = rm - y*28;
      int dp = d-3; if (dp<0) dp+=28;
      int yp = y-3; if (yp<0) yp+=28;
      int xq = x-3; if (xq<0) xq+=28;
      int nd = dp/7, i = dp - nd*7;
      int nh = yp/7, j = yp - nh*7;
      int nw = xq/7, k2 = xq - nw*7;
      src = ((nd*4+nh)*4+nw)*NTOK + (i*7+j)*7 + k2;
    }
    map[tid] = src;
  }
  __syncthreads();
  int sv = tid>>2, c8 = (tid&3)*8;
  int arow = map[sv];
  int lane = tid&63, wv = tid>>6;
  int lm = lane&15, lq = lane>>4;
  int mbase = (wv>>1)*32, nbase = (wv&1)*32;

  float4v acc[2][2];
  #pragma unroll
  for (int mt=0; mt<2; mt++)
    #pragma unroll
    for (int nt=0; nt<2; nt++) acc[mt][nt] = (float4v)0.f;

  float4 afr0, afr1; uint4 abr; uint4 bvr;
  auto load_s = [&](int s){
    if (ASRC == 0){
      const float* ap = Af + (size_t)arow*K + s*32 + c8;
      afr0 = *(const float4*)ap;
      afr1 = *(const float4*)(ap+4);
    } else {
      abr = *(const uint4*)(Ab + (size_t)arow*K + s*32 + c8);
    }
    bvr = *(const uint4*)(B + (size_t)(ncol0 + sv)*K + s*32 + c8);
  };
  auto write_s = [&](int buf){
    if (ASRC == 0){
      uint4 pk;
      pk.x = (u32)f2b(afr0.x) | ((u32)f2b(afr0.y)<<16);
      pk.y = (u32)f2b(afr0.z) | ((u32)f2b(afr0.w)<<16);
      pk.z = (u32)f2b(afr1.x) | ((u32)f2b(afr1.y)<<16);
      pk.w = (u32)f2b(afr1.z) | ((u32)f2b(afr1.w)<<16);
      *(uint4*)(&As[buf][sv*40 + c8]) = pk;
    } else {
      *(uint4*)(&As[buf][sv*40 + c8]) = abr;
    }
    *(uint4*)(&Bs[buf][sv*40 + c8]) = bvr;
  };

  load_s(0);
  write_s(0);
  __syncthreads();
  for (int s = 0; s < STEPS; s++){
    if (s+1 < STEPS) load_s(s+1);
    int buf = s&1;
    short8 aa[2], bb[2];
    #pragma unroll
    for (int mt=0; mt<2; mt++)
      aa[mt] = *(const short8*)(&As[buf][(mbase + mt*16 + lm)*40 + lq*8]);
    #pragma unroll
    for (int nt=0; nt<2; nt++)
      bb[nt] = *(const short8*)(&Bs[buf][(nbase + nt*16 + lm)*40 + lq*8]);
    #pragma unroll
    for (int nt=0; nt<2; nt++)
      #pragma unroll
      for (int mt=0; mt<2; mt++)
        acc[mt][nt] = __builtin_amdgcn_mfma_f32_16x16x32_bf16(aa[mt], bb[nt], acc[mt][nt], 0, 0, 0);
    if (s+1 < STEPS) write_s((s+1)&1);
    __syncthreads();
  }
  // epilogue
  float bv[2];
  #pragma unroll
  for (int nt=0; nt<2; nt++) bv[nt] = bias ? bias[ncol0 + nbase + nt*16 + lm] : 0.f;
  #pragma unroll
  for (int mt=0; mt<2; mt++){
    #pragma unroll
    for (int r=0; r<4; r++){
      int row = v0 + mbase + mt*16 + lq*4 + r;
      if (EPI == 0 || EPI == 3){
        int w = row/343; int tok = row - w*343;
        #pragma unroll
        for (int nt=0; nt<2; nt++){
          int col = ncol0 + nbase + nt*16 + lm;
          float val = (acc[mt][nt][r] + bv[nt]) * scale;
          if (EPI == 0){
            int h = col>>5, c = col&31;
            out16[((size_t)(w*6 + h)*343 + tok)*32 + c] = f2b(val);
          } else {
            u16* dst = (col < 192) ? out16 : out16b;
            int cc = (col < 192) ? col : col - 192;
            int h = cc>>5, c = cc&31;
            dst[((size_t)(w*6 + h)*343 + tok)*32 + c] = f2b(val);
          }
        }
      } else if (EPI == 1){
        #pragma unroll
        for (int nt=0; nt<2; nt++){
          int col = ncol0 + nbase + nt*16 + lm;
          size_t o = (size_t)row*NF + col;
          outf[o] = acc[mt][nt][r] + bv[nt] + resid[o];
        }
      } else {
        #pragma unroll
        for (int nt=0; nt<2; nt++){
          int col = ncol0 + nbase + nt*16 + lm;
          float v = acc[mt][nt][r] + bv[nt];
          float gl = 0.5f*v*(1.f + erff(v*0.70710678118f));
          out16[(size_t)row*NF + col] = f2b(gl);
        }
      }
    }
  }
}

// ---- BN stats, coalesced 2-stage: partial sums then finalize --------------
__global__ __launch_bounds__(192) void k_bnsum(const float* __restrict__ x, int C,
                                               float* __restrict__ psum){
  int bid = blockIdx.x, t = threadIdx.x;
  int rpi = 192/C;
  int c  = (C==192) ? t : (t % 96);
  int ro = (C==192) ? 0 : (t / 96);
  float s=0.f, s2=0.f;
  int base = bid*343;
  for (int r = ro; r < 343; r += rpi){
    float v = x[(size_t)(base+r)*C + c];
    s += v; s2 += v*v;
  }
  psum[(size_t)bid*384 + t]       = s;
  psum[(size_t)bid*384 + 192 + t] = s2;
}
__global__ void k_bnfin(const float* __restrict__ psum, int C,
                        const float* __restrict__ g, const float* __restrict__ b,
                        float* __restrict__ a_out, float* __restrict__ b_out){
  int c = threadIdx.x;
  if (c >= C) return;
  int slots = 192/C;
  float s=0.f, s2=0.f;
  for (int bb=0; bb<64; bb++)
    for (int k=0; k<slots; k++){
      s  += psum[(size_t)bb*384 + k*C + c];
      s2 += psum[(size_t)bb*384 + 192 + k*C + c];
    }
  float mu = s/(float)LTOT;
  float var = s2/(float)LTOT - mu*mu;
  float rstd = rsqrtf(var + 1e-5f);
  float aa = rstd * g[c];
  a_out[c] = aa;
  b_out[c] = b[c] - mu*aa;
}

// ------------- conv3 1x1x1: 96 -> 18 flow channels, layout (18, L) ---------
__global__ __launch_bounds__(96) void k_flow(const float* __restrict__ t2,
                                             const float* __restrict__ a2, const float* __restrict__ b2,
                                             const float* __restrict__ w3, float* __restrict__ flow){
  __shared__ float xr[96];
  int l = blockIdx.x; int t = threadIdx.x;
  float xv = t2[(size_t)l*96 + t];
  xr[t] = fmaxf(xv*a2[t] + b2[t], 0.f);
  __syncthreads();
  if (t < 18){
    float acc = 0.f;
    for (int c=0;c<96;c++) acc += xr[c]*w3[t*96 + c];
    flow[(size_t)t*LTOT + l] = acc;
  }
}

// ------------- trilinear warp (per-head flow), border clamp ----------------
__global__ __launch_bounds__(192) void k_warp(const float* __restrict__ src,
                                              const float* __restrict__ flow, float* __restrict__ dst){
  int l = blockIdx.x; int tid = threadIdx.x; int hh = tid>>5;
  int d = l/784; int rm = l - d*784; int y = rm/28; int x = rm - y*28;
  float fd = flow[(size_t)(hh*3+0)*LTOT + l];
  float fy = flow[(size_t)(hh*3+1)*LTOT + l];
  float fx = flow[(size_t)(hh*3+2)*LTOT + l];
  float cd = fminf(fmaxf((float)d + fd, 0.f), 27.f);
  float cy = fminf(fmaxf((float)y + fy, 0.f), 27.f);
  float cx = fminf(fmaxf((float)x + fx, 0.f), 27.f);
  int d0 = (int)floorf(cd); int d1 = min(d0+1, 27);
  int y0 = (int)floorf(cy); int y1 = min(y0+1, 27);
  int x0 = (int)floorf(cx); int x1 = min(x0+1, 27);
  float wd = cd - (float)d0, wy = cy - (float)y0, wx = cx - (float)x0;
  #define SMP(di,yi,xi) src[(size_t)(((di)*28+(yi))*28+(xi))*192 + tid]
  float v000 = SMP(d0,y0,x0), v001 = SMP(d0,y0,x1), v010 = SMP(d0,y1,x0), v011 = SMP(d0,y1,x1);
  float v100 = SMP(d1,y0,x0), v101 = SMP(d1,y0,x1), v110 = SMP(d1,y1,x0), v111 = SMP(d1,y1,x1);
  #undef SMP
  float o = v000*(1-wd)*(1-wy)*(1-wx) + v001*(1-wd)*(1-wy)*wx
          + v010*(1-wd)*wy*(1-wx)     + v011*(1-wd)*wy*wx
          + v100*wd*(1-wy)*(1-wx)     + v101*wd*(1-wy)*wx
          + v110*wd*wy*(1-wx)         + v111*wd*wy*wx;
  dst[(size_t)l*192 + tid] = o;
}

// ------------ MFMA attention: block = (window, head, q-group) --------------
__global__ __launch_bounds__(256) void k_attmfma(const u16* __restrict__ Q,
                                                 const u16* __restrict__ K,
                                                 const u16* __restrict__ V,
                                                 const float* __restrict__ bm,
                                                 float* __restrict__ ctx){
  __shared__ __align__(16) u16 Kl[352*40];      // [key][40]
  __shared__ __align__(16) u16 Vt[32*360];      // [dim][360]
  __shared__ __align__(16) u16 Pl[4][2][16*40]; // per-wave, dbuf
  int bid = blockIdx.x;
  int wh = bid/6, qg = bid - (bid/6)*6;
  int w = wh/6, h = wh - w*6;
  int tid = threadIdx.x;
  int nd = w>>4, nh = (w>>2)&3, nw = w&3;
  int type = ((nd==3)?4:0) | ((nh==3)?2:0) | ((nw==3)?1:0);
  const u16* kb = K + (size_t)wh*10976;
  const u16* vbp = V + (size_t)wh*10976;
  for (int idx=tid; idx<343*4; idx+=256){
    int row = idx>>2, c8 = (idx&3)*8;
    uint4 val = *(const uint4*)(kb + row*32 + c8);
    *(uint4*)(&Kl[row*40 + c8]) = val;
  }
  for (int idx=tid; idx<9*40; idx+=256) Kl[343*40 + idx] = 0;
  for (int idx=tid; idx<343*4; idx+=256){
    int row = idx>>2, c8 = (idx&3)*8;
    uint4 val = *(const uint4*)(vbp + row*32 + c8);
    const u16* pv = (const u16*)&val;
    #pragma unroll
    for (int j=0;j<8;j++) Vt[(c8+j)*360 + row] = pv[j];
  }
  for (int idx=tid; idx<32*17; idx+=256){
    int dd = idx/17, cc = 343 + idx - (idx/17)*17;
    Vt[dd*360 + cc] = 0;
  }
  __syncthreads();
  int lane = tid&63, wv = tid>>6;
  int lm = lane&15, lq = lane>>4;
  const float* bmh = bm + (size_t)(type*6 + h)*123904;
  int qt = qg*4 + wv;
  if (qt < 22){
    int q0 = qt*16;
    short8 bq = *(const short8*)(Q + (size_t)wh*10976 + (q0+lm)*32 + lq*8);
    float4v sc[22];
    #pragma unroll
    for (int kt=0; kt<22; kt++){
      short8 ak = *(const short8*)(&Kl[(kt*16+lm)*40 + lq*8]);
      sc[kt] = __builtin_amdgcn_mfma_f32_16x16x32_bf16(ak, bq, (float4v)0.f, 0, 0, 0);
    }
    const float* bcol = bmh + q0 + lm;
    float mx = -3.0e38f;
    #pragma unroll
    for (int kt=0; kt<22; kt++){
      #pragma unroll
      for (int r=0; r<4; r++){
        int key = kt*16 + lq*4 + r;
        float s = sc[kt][r] + bcol[(size_t)key*352];
        sc[kt][r] = s;
        mx = fmaxf(mx, s);
      }
    }
    mx = fmaxf(mx, __shfl_xor(mx, 16));
    mx = fmaxf(mx, __shfl_xor(mx, 32));
    float sm = 0.f;
    #pragma unroll
    for (int kt=0; kt<22; kt++){
      #pragma unroll
      for (int r=0; r<4; r++){
        float p = __expf(sc[kt][r] - mx);
        sc[kt][r] = p;
        sm += p;
      }
    }
    sm += __shfl_xor(sm, 16);
    sm += __shfl_xor(sm, 32);
    float inv = 1.f/sm;
    float4v o0 = (float4v)0.f, o1 = (float4v)0.f;
    #pragma unroll
    for (int s=0; s<11; s++){
      u16* pw = &Pl[wv][s&1][0];
      #pragma unroll
      for (int half=0; half<2; half++){
        int kt = 2*s + half;
        uint2 pv2;
        pv2.x = (u32)f2b(sc[kt][0]) | ((u32)f2b(sc[kt][1])<<16);
        pv2.y = (u32)f2b(sc[kt][2]) | ((u32)f2b(sc[kt][3])<<16);
        *(uint2*)(&pw[lm*40 + half*16 + lq*4]) = pv2;
      }
      short8 bp = *(const short8*)(&pw[lm*40 + lq*8]);
      short8 a0 = *(const short8*)(&Vt[lm*360 + s*32 + lq*8]);
      short8 a1 = *(const short8*)(&Vt[(16+lm)*360 + s*32 + lq*8]);
      o0 = __builtin_amdgcn_mfma_f32_16x16x32_bf16(a0, bp, o0, 0, 0, 0);
      o1 = __builtin_amdgcn_mfma_f32_16x16x32_bf16(a1, bp, o1, 0, 0, 0);
    }
    int query = q0 + lm;
    if (query < 343){
      float* ob = ctx + ((size_t)w*NTOK + query)*192 + h*32;
      float4 t0, t1v;
      t0.x = o0[0]*inv; t0.y = o0[1]*inv; t0.z = o0[2]*inv; t0.w = o0[3]*inv;
      t1v.x = o1[0]*inv; t1v.y = o1[1]*inv; t1v.z = o1[2]*inv; t1v.w = o1[3]*inv;
      *(float4*)(ob + lq*4) = t0;
      *(float4*)(ob + 16 + lq*4) = t1v;
    }
  }
}

// ===========================================================================
extern "C" void kernel_launch(void* const* d_in, const int* in_sizes, int n_in,
                              void* d_out, int out_size, void* d_ws, size_t ws_size,
                              hipStream_t stream){
  const float* mov     = (const float*)d_in[0];
  const float* fix     = (const float*)d_in[1];
  const float* n1g     = (const float*)d_in[2];
  const float* n1b     = (const float*)d_in[3];
  const float* offm_w1 = (const float*)d_in[4];
  const float* offm_g1 = (const float*)d_in[5];
  const float* offm_b1 = (const float*)d_in[6];
  const float* offm_w2 = (const float*)d_in[7];
  const float* offm_g2 = (const float*)d_in[8];
  const float* offm_b2 = (const float*)d_in[9];
  const float* offm_w3 = (const float*)d_in[10];
  const float* offf_w1 = (const float*)d_in[11];
  const float* offf_g1 = (const float*)d_in[12];
  const float* offf_b1 = (const float*)d_in[13];
  const float* offf_w2 = (const float*)d_in[14];
  const float* offf_g2 = (const float*)d_in[15];
  const float* offf_b2 = (const float*)d_in[16];
  const float* offf_w3 = (const float*)d_in[17];
  const float* mq_w    = (const float*)d_in[18];
  const float* mkv_w   = (const float*)d_in[19];
  const float* fq_w    = (const float*)d_in[20];
  const float* fkv_w   = (const float*)d_in[21];
  const float* mproj_w = (const float*)d_in[22];
  const float* fproj_w = (const float*)d_in[23];
  const float* mq_b    = (const float*)d_in[24];
  const float* mkv_b   = (const float*)d_in[25];
  const float* fq_b    = (const float*)d_in[26];
  const float* fkv_b   = (const float*)d_in[27];
  const float* mproj_b = (const float*)d_in[28];
  const float* fproj_b = (const float*)d_in[29];
  const float* rpbt    = (const float*)d_in[30];
  const float* n2g     = (const float*)d_in[31];
  const float* n2b     = (const float*)d_in[32];
  const float* fc1_w   = (const float*)d_in[33];
  const float* fc1_b   = (const float*)d_in[34];
  const float* fc2_w   = (const float*)d_in[35];
  const float* fc2_b   = (const float*)d_in[36];
  float* outp = (float*)d_out;

  float* W = (float*)d_ws;
  const size_t L192 = (size_t)LTOT*192;   // floats per region (16.86 MB)
  // conv-phase layout (no overlaps):
  float* m_   = W;                         // region 0
  float* f_   = W + 1*L192;                // region 1
  float* t1m  = W + 2*L192;                // region 2
  float* t1f  = W + 3*L192;                // region 3
  u16* xp     = (u16*)(W + 4*L192);        // 20.74 MB (region 4 + head of 5)
  u16* xp2m   = xp + (size_t)27000*384;    // 10.37 MB (inside region 5)
  u16* xp2f   = (u16*)(W + 6*L192);        // 10.37 MB (head of region 6)
  float* sb   = W + 6*L192 + 3000000;      // stats block (region 6 + 12 MB)
  float* a1m = sb,       *b1m = sb+192;
  float* a1f = sb+384,   *b1f = sb+576;
  float* a2m = sb+768,   *b2m = sb+864;
  float* a2f = sb+960,   *b2f = sb+1056;
  float* psum = sb + 1152;                 // 64*384 floats
  float* flowm = W + 6*L192 + 3100000;     // region 6 + 12.4 MB
  float* flowf = flowm + (size_t)LTOT*18;
  float* t2m  = W + 7*L192;                // region 7 first half
  float* t2f  = W + 7*L192 + (size_t)LTOT*96;  // region 7 second half
  u16* wt1m = (u16*)(W + 8*L192);          // conv weights, region 8
  u16* wt1f = wt1m + 192*10368;
  u16* wt2m = wt1f + 192*10368;
  u16* wt2f = wt2m + 96*5184;
  // post-conv reuse:
  float* dmov = W + 4*L192;
  float* dfix = W + 5*L192;
  float* ctxm = dmov; float* ctxf = dfix;
  float* mout = m_;   float* fout = f_;
  u16* QMb = (u16*)(W + 6*L192);
  u16* QFb = (u16*)(W + 7*L192);
  u16* Kmb = (u16*)(W + 2*L192);
  u16* Vmb = (u16*)(W + 3*L192);
  u16* Kfb = (u16*)(W + 8*L192);
  u16* Vfb = (u16*)(W + 9*L192);
  float* bm = W;
  u16* wq_m  = (u16*)(W + 9*L192) + 4214784;
  u16* wq_f  = wq_m  + 36864;
  u16* wkv_m = wq_f  + 36864;
  u16* wkv_f = wkv_m + 73728;
  u16* wpj_m = wkv_f + 73728;
  u16* wpj_f = wpj_m + 36864;
  u16* wfc1  = wpj_f + 36864;
  u16* wfc2  = wfc1  + 147456;
  u16* hs16  = (u16*)(W + 2*L192);
  float* lnbuf = W + 6*L192;

  // conv weight prep
  k_prepw1b<<<(192*10368+255)/256, 256, 0, stream>>>(offm_w1, wt1m, 0);
  k_prepw1b<<<(192*10368+255)/256, 256, 0, stream>>>(offf_w1, wt1f, 192);
  k_prepw2b<<<(96*5184+255)/256, 256, 0, stream>>>(offm_w2, wt2m);
  k_prepw2b<<<(96*5184+255)/256, 256, 0, stream>>>(offf_w2, wt2f);
  // GEMM weight prep (f32 -> bf16, same layout)
  k_prepwb<<<144, 256, 0, stream>>>(mq_w,    wq_m,  36864);
  k_prepwb<<<144, 256, 0, stream>>>(fq_w,    wq_f,  36864);
  k_prepwb<<<288, 256, 0, stream>>>(mkv_w,   wkv_m, 73728);
  k_prepwb<<<288, 256, 0, stream>>>(fkv_w,   wkv_f, 73728);
  k_prepwb<<<144, 256, 0, stream>>>(mproj_w, wpj_m, 36864);
  k_prepwb<<<144, 256, 0, stream>>>(fproj_w, wpj_f, 36864);
  k_prepwb<<<576, 256, 0, stream>>>(fc1_w,   wfc1,  147456);
  k_prepwb<<<576, 256, 0, stream>>>(fc2_w,   wfc2,  147456);
  // layernorm1
  k_ln<<<2*LTOT, 64, 0, stream>>>(mov, fix, n1g, n1b, m_, f_);
  // padded bf16 volume [m|f]
  k_pad1<<<27000, 192, 0, stream>>>(m_, f_, xp);
  // offset block conv1: m+f fused, full-N blocks (grid 686)
  k_convmfma<384,192><<<686, 256, 0, stream>>>(xp, xp, wt1m, wt1f, t1m, t1f);
  k_bnsum<<<64, 192, 0, stream>>>(t1m, 192, psum);
  k_bnfin<<<1, 192, 0, stream>>>(psum, 192, offm_g1, offm_b1, a1m, b1m);
  k_bnsum<<<64, 192, 0, stream>>>(t1f, 192, psum);
  k_bnfin<<<1, 192, 0, stream>>>(psum, 192, offf_g1, offf_b1, a1f, b1f);
  k_pad2<<<27000, 192, 0, stream>>>(t1m, a1m, b1m, xp2m);
  k_pad2<<<27000, 192, 0, stream>>>(t1f, a1f, b1f, xp2f);
  // conv2: m+f fused
  k_convmfma<192,96><<<686, 256, 0, stream>>>(xp2m, xp2f, wt2m, wt2f, t2m, t2f);
  k_bnsum<<<64, 192, 0, stream>>>(t2m, 96, psum);
  k_bnfin<<<1, 96, 0, stream>>>(psum, 96, offm_g2, offm_b2, a2m, b2m);
  k_bnsum<<<64, 192, 0, stream>>>(t2f, 96, psum);
  k_bnfin<<<1, 96, 0, stream>>>(psum, 96, offf_g2, offf_b2, a2f, b2f);
  k_flow<<<LTOT, 96, 0, stream>>>(t2m, a2m, b2m, offm_w3, flowm);
  k_flow<<<LTOT, 96, 0, stream>>>(t2f, a2f, b2f, offf_w3, flowf);
  // deformable warp
  k_warp<<<LTOT, 192, 0, stream>>>(m_, flowm, dmov);
  k_warp<<<LTOT, 192, 0, stream>>>(f_, flowf, dfix);
  // windowed projections (MFMA GEMM, gather folded into A-map) -> bf16
  const float scale = 0.17677669529663687f; // 32^-0.5
  k_gemm<192,192,1,0,0><<<343*3, 256, 0, stream>>>(dmov, nullptr, wq_m,  mq_b,  nullptr, nullptr, QMb, nullptr, scale);
  k_gemm<192,192,1,0,0><<<343*3, 256, 0, stream>>>(dfix, nullptr, wq_f,  fq_b,  nullptr, nullptr, QFb, nullptr, scale);
  k_gemm<192,384,1,0,3><<<343*6, 256, 0, stream>>>(m_,   nullptr, wkv_m, mkv_b, nullptr, nullptr, Kmb, Vmb, 1.f);
  k_gemm<192,384,1,0,3><<<343*6, 256, 0, stream>>>(f_,   nullptr, wkv_f, fkv_b, nullptr, nullptr, Kfb, Vfb, 1.f);
  // bias matrix (m_/f_ now dead)
  k_prepbias<<<(48*123904+255)/256, 256, 0, stream>>>(rpbt, bm);
  // attention: mo = attend(dfQ, mK, mV); fo = attend(dmQ, fK, fV)
  k_attmfma<<<2304, 256, 0, stream>>>(QFb, Kmb, Vmb, bm, ctxm);
  k_attmfma<<<2304, 256, 0, stream>>>(QMb, Kfb, Vfb, bm, ctxf);
  // proj + residual + window-reverse (gather on A rows)
  k_gemm<192,192,2,0,1><<<343*3, 256, 0, stream>>>(ctxm, nullptr, wpj_m, mproj_b, mov, mout, nullptr, nullptr, 1.f);
  k_gemm<192,192,2,0,1><<<343*3, 256, 0, stream>>>(ctxf, nullptr, wpj_f, fproj_b, fix, fout, nullptr, nullptr, 1.f);
  // MLP (mov half): LN -> fc1(gelu, bf16 hs) -> fc2(+resid)
  k_ln1<<<LTOT, 64, 0, stream>>>(mout, n2g, n2b, lnbuf);
  k_gemm<192,768,0,0,2><<<343*12, 256, 0, stream>>>(lnbuf, nullptr, wfc1, fc1_b, nullptr, nullptr, hs16, nullptr, 1.f);
  k_gemm<768,192,0,1,1><<<343*3, 256, 0, stream>>>(nullptr, hs16, wfc2, fc2_b, mout, outp, nullptr, nullptr, 1.f);
  // MLP (fix half)
  k_ln1<<<LTOT, 64, 0, stream>>>(fout, n2g, n2b, lnbuf);
  k_gemm<192,768,0,0,2><<<343*12, 256, 0, stream>>>(lnbuf, nullptr, wfc1, fc1_b, nullptr, nullptr, hs16, nullptr, 1.f);
  k_gemm<768,192,0,1,1><<<343*3, 256, 0, stream>>>(nullptr, hs16, wfc2, fc2_b, fout, outp + L192, nullptr, nullptr, 1.f);
}